// Round 13
// baseline (1062.160 us; speedup 1.0000x reference)
//
#include <hip/hip_runtime.h>
#include <math.h>

#define DIM 512
#define NH 8
#define HD 64
#define SEQ 2048
#define BATCH 2
#define NLAYER 4
#define FFD 2048
#define VOCAB 32000
#define ROWS (BATCH*SEQ)   // 4096
#define QKV_LD 1536

typedef unsigned short u16;
typedef __attribute__((ext_vector_type(8))) short bfrag;   // 8 x bf16 (4 VGPRs)
typedef __attribute__((ext_vector_type(4))) short sfrag4;  // 4 x bf16 (8B)
typedef __attribute__((ext_vector_type(4))) float facc;    // 4 x f32

__device__ __forceinline__ u16 f2bf(float f){
  unsigned u = __builtin_bit_cast(unsigned, f);
  u += 0x7fff + ((u>>16)&1);          // RNE
  return (u16)(u>>16);
}

typedef __attribute__((address_space(3))) unsigned int lds_u32;
typedef const __attribute__((address_space(1))) unsigned int glob_u32;
__device__ __forceinline__ void gload16(const void* g, void* l){
  __builtin_amdgcn_global_load_lds((glob_u32*)g, (lds_u32*)l, 16, 0, 0);
}

template<int N> __device__ __forceinline__ void wait_vmcnt(){
  if constexpr (N==0)       asm volatile("s_waitcnt vmcnt(0)" ::: "memory");
  else if constexpr (N==3)  asm volatile("s_waitcnt vmcnt(3)" ::: "memory");
  else if constexpr (N==4)  asm volatile("s_waitcnt vmcnt(4)" ::: "memory");
  else if constexpr (N==6)  asm volatile("s_waitcnt vmcnt(6)" ::: "memory");
  else if constexpr (N==8)  asm volatile("s_waitcnt vmcnt(8)" ::: "memory");
  else if constexpr (N==16) asm volatile("s_waitcnt vmcnt(16)" ::: "memory");
  else static_assert(N==0, "unsupported vmcnt");
}

// ============ unified preprocessing: 9 transposes + 2 bias concats ===========
__device__ __forceinline__ void do_transpose(
    const float* __restrict__ I, u16* __restrict__ O,
    int K, int N, int nx, int ky, int imode){
  __shared__ float t[32][33];
  const int n0 = nx*32, k0 = ky*32;
  #pragma unroll
  for (int i=0;i<4;i++){
    int k = k0 + threadIdx.y + 8*i;
    t[threadIdx.y+8*i][threadIdx.x] = I[(size_t)k*N + n0 + threadIdx.x];
  }
  __syncthreads();
  #pragma unroll
  for (int i=0;i<4;i++){
    int n = n0 + threadIdx.y + 8*i;
    int np = (imode==0) ? n : ((n>>4)*32 + (n&15) + (imode==2 ? 16 : 0));
    O[(size_t)np*K + k0 + threadIdx.x] = f2bf(t[threadIdx.x][threadIdx.y+8*i]);
  }
}

__global__ void pre_all(
    const float* qw, const float* kw, const float* vw, const float* ow,
    const float* iw, const float* gw, const float* f1w, const float* f2w,
    const float* outw,
    const float* qb, const float* kb, const float* vb,
    const float* ib, const float* gb,
    u16* qkvT, u16* owT, u16* igT, u16* f1T, u16* f2T, u16* outT,
    float* qkvb, float* igb){
  const int bid = blockIdx.x;
  if (bid < 6144){                                   // jobs 0-5: 512x512 per layer
    int job = bid >> 10, local = bid & 1023;
    int l = local >> 8, rr = local & 255;
    int nx = rr & 15, ky = rr >> 4;
    const float* src; u16* dst; int im = 0;
    switch(job){
      case 0: src=qw+(size_t)l*262144; dst=qkvT+(size_t)l*786432;        break;
      case 1: src=kw+(size_t)l*262144; dst=qkvT+(size_t)l*786432+262144; break;
      case 2: src=vw+(size_t)l*262144; dst=qkvT+(size_t)l*786432+524288; break;
      case 3: src=ow+(size_t)l*262144; dst=owT +(size_t)l*262144;        break;
      case 4: src=iw+(size_t)l*262144; dst=igT +(size_t)l*524288; im=1;  break;
      default:src=gw+(size_t)l*262144; dst=igT +(size_t)l*524288; im=2;  break;
    }
    do_transpose(src, dst, 512, 512, nx, ky, im);
  } else if (bid < 10240){                           // job 6: f1w 512x2048
    int local = bid - 6144;
    int l = local >> 10, rr = local & 1023;
    int nx = rr & 63, ky = rr >> 6;
    do_transpose(f1w+(size_t)l*1048576, f1T+(size_t)l*1048576, 512, 2048, nx, ky, 0);
  } else if (bid < 14336){                           // job 7: f2w 2048x512
    int local = bid - 10240;
    int l = local >> 10, rr = local & 1023;
    int nx = rr & 15, ky = rr >> 4;
    do_transpose(f2w+(size_t)l*1048576, f2T+(size_t)l*1048576, 2048, 512, nx, ky, 0);
  } else if (bid < 30336){                           // job 8: outw 512x32000
    int local = bid - 14336;
    int nx = local % 1000, ky = local / 1000;
    do_transpose(outw, outT, 512, 32000, nx, ky, 0);
  } else if (bid < 30360){                           // concat3: qkv bias
    int tid = threadIdx.y*32 + threadIdx.x;
    int idx = (bid-30336)*256 + tid;                 // < 6144
    int l = idx/1536, r2 = idx%1536;
    qkvb[idx] = (r2<512) ? qb[l*512+r2] : (r2<1024 ? kb[l*512+r2-512] : vb[l*512+r2-1024]);
  } else {                                           // concat2i: interleaved i/g bias
    int tid = threadIdx.y*32 + threadIdx.x;
    int idx = (bid-30360)*256 + tid;                 // < 4096
    int l = idx>>10, cp = idx&1023;
    int bb = cp>>4, c = (bb>>1)*16 + (cp&15);
    igb[idx] = (bb&1) ? gb[l*512+c] : ib[l*512+c];
  }
}

// ---------------- embedding ---------------------------------------------------
__global__ void embed_k(const int* __restrict__ x, const float* __restrict__ tok,
                        const float* __restrict__ pos, float* __restrict__ h){
  int idx = blockIdx.x*256 + threadIdx.x;     // over ROWS*DIM/4
  int row = idx >> 7;
  int d4  = idx & 127;
  int s   = row & (SEQ-1);
  int tkn = x[row];
  float4 tv = *(const float4*)(tok + (size_t)tkn*DIM + d4*4);
  float4 pv = *(const float4*)(pos + (size_t)s*DIM + d4*4);
  float4 r; r.x=tv.x+pv.x; r.y=tv.y+pv.y; r.z=tv.z+pv.z; r.w=tv.w+pv.w;
  *(float4*)(h + (size_t)row*DIM + d4*4) = r;
}

// ---------------- layernorm: f32 in -> bf16 out ------------------------------
__global__ __launch_bounds__(256) void ln_k(const float* __restrict__ h,
    const float* __restrict__ w, const float* __restrict__ bsc,
    u16* __restrict__ out){
  const int wid = threadIdx.x>>6, lane = threadIdx.x&63;
  const int row = blockIdx.x*4 + wid;
  const float* r = h + (size_t)row*DIM + lane*8;
  float4 v0 = *(const float4*)r;
  float4 v1 = *(const float4*)(r+4);
  float s  = v0.x+v0.y+v0.z+v0.w + v1.x+v1.y+v1.z+v1.w;
  float ss = v0.x*v0.x+v0.y*v0.y+v0.z*v0.z+v0.w*v0.w
           + v1.x*v1.x+v1.y*v1.y+v1.z*v1.z+v1.w*v1.w;
  #pragma unroll
  for (int m=1;m<64;m<<=1){ s += __shfl_xor(s,m); ss += __shfl_xor(ss,m); }
  const float mean = s*(1.f/DIM);
  const float var  = ss*(1.f/DIM) - mean*mean;
  const float rsd  = rsqrtf(var + 1e-5f);
  float4 w0 = *(const float4*)(w + lane*8);
  float4 w1 = *(const float4*)(w + lane*8 + 4);
  float4 b0 = *(const float4*)(bsc + lane*8);
  float4 b1 = *(const float4*)(bsc + lane*8 + 4);
  bfrag pk;
  pk[0]=(short)f2bf((v0.x-mean)*rsd*w0.x+b0.x);
  pk[1]=(short)f2bf((v0.y-mean)*rsd*w0.y+b0.y);
  pk[2]=(short)f2bf((v0.z-mean)*rsd*w0.z+b0.z);
  pk[3]=(short)f2bf((v0.w-mean)*rsd*w0.w+b0.w);
  pk[4]=(short)f2bf((v1.x-mean)*rsd*w1.x+b1.x);
  pk[5]=(short)f2bf((v1.y-mean)*rsd*w1.y+b1.y);
  pk[6]=(short)f2bf((v1.z-mean)*rsd*w1.z+b1.z);
  pk[7]=(short)f2bf((v1.w-mean)*rsd*w1.w+b1.w);
  *(bfrag*)&out[(size_t)row*DIM + lane*8] = pk;
}

// ---------------- pipelined GEMM: C[M,N] = A[M,K](bf16) * BT[N,K]^T + bias ---
// MODE 0: Cf = v                        3: Cb = bf16(gelu(v))
// MODE 4: t=Cf+v; t*=cos(aux[col]*t); Cf=t        (residual+superpos)
// MODE 5: interleaved i/g gate: Cf = i*sig(g) + Cf*(1-sig(g))
// MODE 6: t=Cf+v; Cf=t; Cb=bf16(t)                (residual + tobf)
// MODE 7: cols<1024 -> Cb (qkv); cols>=1024 -> vt transposed (V^T)
// MODE 8: Cf = v via nontemporal store (streaming logits)
template<int BM,int BN,int BK,int WRN,int WCN,int DEPTH,int MODE,int SWZ>
__global__ __launch_bounds__(WRN*WCN*64, 2) void gemm_p(
    const u16* __restrict__ A, const u16* __restrict__ BT,
    const float* __restrict__ bias, const float* __restrict__ aux,
    float* __restrict__ Cf, u16* __restrict__ Cb, u16* __restrict__ vt,
    int M, int N, int K){
  constexpr int NTH = WRN*WCN*64;
  constexpr int FI  = BM/(16*WRN);
  constexpr int FJ  = BN/(16*WCN);
  constexpr int CPR = BK/8;
  constexpr int LA  = BM*CPR/NTH;
  constexpr int LB  = BN*CPR/NTH;
  constexpr int LPT = LA+LB;
  constexpr int NKK = BK/32;
  extern __shared__ __align__(16) u16 smem[];
  u16* lds_a = smem;                     // [DEPTH][BM*BK]
  u16* lds_b = smem + DEPTH*BM*BK;       // [DEPTH][BN*BK]

  const int tid = threadIdx.x;
  const int wid = tid>>6, lane = tid&63;
  const int wr = wid / WCN, wc = wid % WCN;
  const int lr = lane&15, lg = lane>>4;
  int tm, tn;
  if constexpr (SWZ){
    const unsigned nwg = gridDim.x*gridDim.y;
    const unsigned lin = blockIdx.y*gridDim.x + blockIdx.x;
    const unsigned q = nwg >> 3;
    const unsigned sw = (lin & 7)*q + (lin >> 3);
    tm = sw % gridDim.x; tn = sw / gridDim.x;
  } else {
    tm = blockIdx.x; tn = blockIdx.y;
  }

  auto swzf = [](int row)->int{ return (BK==64) ? (row&7) : ((row>>1)&3); };

  auto stage = [&](int t, int buf){
    const int k0 = t*BK;
    #pragma unroll
    for (int i=0;i<LA;i++){
      int u = i*NTH + tid;
      int row = u/CPR, c = (u%CPR) ^ swzf(row);
      gload16(&A[(size_t)(tm*BM+row)*K + k0 + c*8], &lds_a[buf*BM*BK + u*8]);
    }
    #pragma unroll
    for (int i=0;i<LB;i++){
      int u = i*NTH + tid;
      int row = u/CPR, c = (u%CPR) ^ swzf(row);
      gload16(&BT[(size_t)(tn*BN+row)*K + k0 + c*8], &lds_b[buf*BN*BK + u*8]);
    }
  };

  facc acc[FI][FJ] = {};
  const int NT = K/BK;
  stage(0,0);
  if (NT>1) stage(1,1);
  if constexpr (DEPTH==3) { if (NT>2) stage(2,2); }
  for (int t=0;t<NT;t++){
    const int buf = t % DEPTH;
    const u16* la = &lds_a[buf*BM*BK];
    const u16* lb = &lds_b[buf*BN*BK];
    const int rem = NT-1-t;
    if constexpr (DEPTH==3){
      if (rem >= 2) wait_vmcnt<2*LPT>();
      else if (rem == 1) wait_vmcnt<LPT>();
      else wait_vmcnt<0>();
    } else {
      if (rem >= 1) wait_vmcnt<LPT>(); else wait_vmcnt<0>();
    }
    __builtin_amdgcn_s_barrier();
    __builtin_amdgcn_sched_barrier(0);
    bfrag af[FI], bf[FJ];
    #pragma unroll
    for (int i=0;i<FI;i++){
      int row = wr*(FI*16) + i*16 + lr;
      af[i] = *(const bfrag*)&la[row*BK + ((lg ^ swzf(row))*8)];
    }
    #pragma unroll
    for (int j=0;j<FJ;j++){
      int row = wc*(FJ*16) + j*16 + lr;
      bf[j] = *(const bfrag*)&lb[row*BK + ((lg ^ swzf(row))*8)];
    }
    if constexpr (NKK==1){
      asm volatile("s_waitcnt lgkmcnt(0)" ::: "memory");
      __builtin_amdgcn_sched_barrier(0);
      __builtin_amdgcn_s_barrier();
      __builtin_amdgcn_sched_barrier(0);
      if (t+DEPTH<NT) stage(t+DEPTH, buf);
      __builtin_amdgcn_s_setprio(1);
      #pragma unroll
      for (int i=0;i<FI;i++)
        #pragma unroll
        for (int j=0;j<FJ;j++)
          acc[i][j] = __builtin_amdgcn_mfma_f32_16x16x32_bf16(af[i], bf[j], acc[i][j],0,0,0);
      __builtin_amdgcn_s_setprio(0);
    } else {
      __builtin_amdgcn_s_setprio(1);
      #pragma unroll
      for (int i=0;i<FI;i++)
        #pragma unroll
        for (int j=0;j<FJ;j++)
          acc[i][j] = __builtin_amdgcn_mfma_f32_16x16x32_bf16(af[i], bf[j], acc[i][j],0,0,0);
      __builtin_amdgcn_s_setprio(0);
      bfrag af1[FI], bf1[FJ];
      #pragma unroll
      for (int i=0;i<FI;i++){
        int row = wr*(FI*16) + i*16 + lr;
        af1[i] = *(const bfrag*)&la[row*BK + (((4+lg) ^ swzf(row))*8)];
      }
      #pragma unroll
      for (int j=0;j<FJ;j++){
        int row = wc*(FJ*16) + j*16 + lr;
        bf1[j] = *(const bfrag*)&lb[row*BK + (((4+lg) ^ swzf(row))*8)];
      }
      asm volatile("s_waitcnt lgkmcnt(0)" ::: "memory");
      __builtin_amdgcn_sched_barrier(0);
      __builtin_amdgcn_s_barrier();
      __builtin_amdgcn_sched_barrier(0);
      if (t+DEPTH<NT) stage(t+DEPTH, buf);
      __builtin_amdgcn_s_setprio(1);
      #pragma unroll
      for (int i=0;i<FI;i++)
        #pragma unroll
        for (int j=0;j<FJ;j++)
          acc[i][j] = __builtin_amdgcn_mfma_f32_16x16x32_bf16(af1[i], bf1[j], acc[i][j],0,0,0);
      __builtin_amdgcn_s_setprio(0);
    }
  }

  if constexpr (MODE==5){
    #pragma unroll
    for (int i=0;i<FI;i++){
      #pragma unroll
      for (int j=0;j<FJ;j+=2){
        const int colp = tn*BN + wc*(FJ*16) + j*16;  // even 16-block (i-half)
        const int c = (colp>>5)*16 + lr;             // true output col
        const float bi = bias[colp + lr];
        const float bg = bias[colp + 16 + lr];
        #pragma unroll
        for (int r=0;r<4;r++){
          const int row = tm*BM + wr*(FI*16) + i*16 + lg*4 + r;
          float vi = acc[i][j][r]   + bi;
          float vg = acc[i][j+1][r] + bg;
          float g  = 1.f/(1.f+__expf(-vg));
          const size_t o = (size_t)row*DIM + c;
          float hv = Cf[o];
          Cf[o] = vi*g + hv*(1.f-g);
        }
      }
    }
  } else if constexpr (MODE==7){
    #pragma unroll
    for (int i=0;i<FI;i++){
      #pragma unroll
      for (int j=0;j<FJ;j++){
        const int colblk = tn*BN + wc*(FJ*16) + j*16;
        const float bv = bias[colblk + lr];
        if (colblk < 1024){
          #pragma unroll
          for (int r=0;r<4;r++){
            const int row = tm*BM + wr*(FI*16) + i*16 + lg*4 + r;
            Cb[(size_t)row*N + colblk + lr] = f2bf(acc[i][j][r] + bv);
          }
        } else {
          const int c = colblk + lr - 1024;
          const int hh = c>>6, d = c&63;
          const int row0 = tm*BM + wr*(FI*16) + i*16 + lg*4;
          const int b = row0>>11, s0 = row0&2047;
          sfrag4 pk;
          #pragma unroll
          for (int r=0;r<4;r++) pk[r] = (short)f2bf(acc[i][j][r] + bv);
          *(sfrag4*)&vt[((size_t)((b*NH+hh)*HD + d))*SEQ + s0] = pk;
        }
      }
    }
  } else {
    #pragma unroll
    for (int i=0;i<FI;i++){
      #pragma unroll
      for (int j=0;j<FJ;j++){
        const int col = tn*BN + wc*(FJ*16) + j*16 + lr;
        const float bv = bias ? bias[col] : 0.f;
        #pragma unroll
        for (int r=0;r<4;r++){
          const int row = tm*BM + wr*(FI*16) + i*16 + lg*4 + r;
          float v = acc[i][j][r] + bv;
          const size_t o = (size_t)row*N + col;
          if      (MODE==0) Cf[o] = v;
          else if (MODE==8) __builtin_nontemporal_store(v, &Cf[o]);
          else if (MODE==3){ float g = 0.5f*v*(1.f+erff(v*0.70710678118f)); Cb[o] = f2bf(g); }
          else if (MODE==4){ float t = Cf[o] + v; t = t*__cosf(aux[col]*t); Cf[o] = t; }
          else if (MODE==6){ float t = Cf[o] + v; Cf[o] = t; Cb[o] = f2bf(t); }
        }
      }
    }
  }
}

// ---------------- fused causal attention (v1 structure, fixed-shift softmax,
// causal pair-remap for load balance) -----------------------------------------
__global__ __launch_bounds__(256) void attn_k(
    const u16* __restrict__ QKV, const u16* __restrict__ VT,
    const float* __restrict__ qphase, u16* __restrict__ O){
  __shared__ __align__(16) u16 lds_p[4][16*32];
  const int bx = blockIdx.x;
  const int qblk = (bx&1) ? (31 - (bx>>1)) : (bx>>1);   // pair-remap: work(i)+work(pair) = const
  const int hh = blockIdx.y, b = blockIdx.z;
  const int tid = threadIdx.x;
  const int wid = tid>>6, lane = tid&63;
  const int lr = lane&15, lg = lane>>4;
  const int qbase = qblk*64 + wid*16;
  const float ph = qphase[hh];
  const float scale = 0.125f;               // 1/sqrt(64)
  u16* pbuf = lds_p[wid];

  bfrag aq[2];
  #pragma unroll
  for (int st=0; st<2; st++)
    aq[st] = *(const bfrag*)&QKV[(size_t)(b*SEQ + qbase + lr)*QKV_LD + hh*HD + st*32 + lg*8];

  facc oacc[4];
  #pragma unroll
  for (int n=0;n<4;n++) oacc[n] = (facc){0.f,0.f,0.f,0.f};
  float lrow[4] = {0.f,0.f,0.f,0.f};

  const int nkv = (qbase + 15)/32 + 1;
  for (int kt=0; kt<nkv; kt++){
    const int kv0 = kt*32;
    facc sc[2];
    #pragma unroll
    for (int j=0;j<2;j++){
      bfrag bk0 = *(const bfrag*)&QKV[(size_t)(b*SEQ + kv0 + j*16 + lr)*QKV_LD + 512 + hh*HD + lg*8];
      bfrag bk1 = *(const bfrag*)&QKV[(size_t)(b*SEQ + kv0 + j*16 + lr)*QKV_LD + 512 + hh*HD + 32 + lg*8];
      facc z = (facc){0.f,0.f,0.f,0.f};
      z     = __builtin_amdgcn_mfma_f32_16x16x32_bf16(aq[0], bk0, z, 0,0,0);
      sc[j] = __builtin_amdgcn_mfma_f32_16x16x32_bf16(aq[1], bk1, z, 0,0,0);
    }
    bfrag vbf[4];
    #pragma unroll
    for (int n=0;n<4;n++)
      vbf[n] = *(const bfrag*)&VT[((size_t)((b*NH + hh)*HD + n*16 + lr))*SEQ + kv0 + lg*8];

    float pv[2][4];
    #pragma unroll
    for (int j=0;j<2;j++)
      #pragma unroll
      for (int r=0;r<4;r++){
        int srow = qbase + lg*4 + r;
        int scol = kv0 + j*16 + lr;
        float xv = sc[j][r]*scale;
        xv = xv*(1.f + 0.1f*__cosf(ph*xv));
        if (scol > srow) xv = -1e30f;
        pv[j][r] = __expf(xv);
      }
    #pragma unroll
    for (int r=0;r<4;r++){
      float rs = pv[0][r] + pv[1][r];
      rs += __shfl_xor(rs,1);
      rs += __shfl_xor(rs,2);
      rs += __shfl_xor(rs,4);
      rs += __shfl_xor(rs,8);
      lrow[r] += rs;
    }
    #pragma unroll
    for (int j=0;j<2;j++)
      #pragma unroll
      for (int r=0;r<4;r++)
        pbuf[(lg*4+r)*32 + j*16 + lr] = f2bf(pv[j][r]);
    bfrag pa = *(const bfrag*)&pbuf[lr*32 + lg*8];
    #pragma unroll
    for (int n=0;n<4;n++)
      oacc[n] = __builtin_amdgcn_mfma_f32_16x16x32_bf16(pa, vbf[n], oacc[n], 0,0,0);
  }
  float rcp[4];
  #pragma unroll
  for (int r=0;r<4;r++) rcp[r] = 1.f/lrow[r];
  #pragma unroll
  for (int n=0;n<4;n++)
    #pragma unroll
    for (int r=0;r<4;r++){
      float val = oacc[n][r] * rcp[r];
      O[(size_t)(b*SEQ + qbase + lg*4 + r)*DIM + hh*HD + n*16 + lr] = f2bf(val);
    }
}

// ---------------- host -------------------------------------------------------
extern "C" void kernel_launch(void* const* d_in, const int* in_sizes, int n_in,
                              void* d_out, int out_size, void* d_ws, size_t ws_size,
                              hipStream_t stream){
  const int*   x        = (const int*)d_in[0];
  const float* tok_emb  = (const float*)d_in[1];
  const float* pos_emb  = (const float*)d_in[2];
  const float* qw = (const float*)d_in[3];  const float* qb = (const float*)d_in[4];
  const float* kw = (const float*)d_in[5];  const float* kb = (const float*)d_in[6];
  const float* vw = (const float*)d_in[7];  const float* vb = (const float*)d_in[8];
  const float* ow = (const float*)d_in[9];  const float* ob = (const float*)d_in[10];
  const float* qphase   = (const float*)d_in[11];
  const float* sp_phase = (const float*)d_in[12];
  const float* n1w = (const float*)d_in[13]; const float* n1b = (const float*)d_in[14];
  const float* n2w = (const float*)d_in[15]; const float* n2b = (const float*)d_in[16];
  const float* f1w = (const float*)d_in[17]; const float* f1b = (const float*)d_in[18];
  const float* f2w = (const float*)d_in[19]; const float* f2b = (const float*)d_in[20];
  const float* iw  = (const float*)d_in[21]; const float* ib  = (const float*)d_in[22];
  const float* gw  = (const float*)d_in[23]; const float* gb  = (const float*)d_in[24];
  const float* nw  = (const float*)d_in[25]; const float* nb  = (const float*)d_in[26];
  const float* outw= (const float*)d_in[27]; const float* outb= (const float*)d_in[28];
  float* out = (float*)d_out;

  char* base = (char*)d_ws;
  size_t off = 0;
  auto alloc = [&](size_t bytes)->void*{
    void* p = base + off; off += bytes; off = (off + 255) & ~(size_t)255; return p;
  };
  float* h    = (float*)alloc((size_t)ROWS*DIM*4);
  u16* hn     = (u16*)alloc((size_t)ROWS*DIM*2);
  u16* qkvB   = (u16*)alloc((size_t)ROWS*QKV_LD*2);
  u16* vTb    = (u16*)alloc((size_t)ROWS*DIM*2);
  u16* oB     = (u16*)alloc((size_t)ROWS*DIM*2);
  u16* hB     = (u16*)alloc((size_t)ROWS*DIM*2);
  u16* ffB    = (u16*)alloc((size_t)ROWS*FFD*2);
  u16* qkvT = (u16*)alloc((size_t)NLAYER*1536*DIM*2);
  u16* owT  = (u16*)alloc((size_t)NLAYER*DIM*DIM*2);
  u16* igT  = (u16*)alloc((size_t)NLAYER*1024*DIM*2);
  u16* f1T  = (u16*)alloc((size_t)NLAYER*DIM*FFD*2);
  u16* f2T  = (u16*)alloc((size_t)NLAYER*DIM*FFD*2);
  u16* outT = (u16*)alloc((size_t)VOCAB*DIM*2);
  float* qkvb = (float*)alloc((size_t)NLAYER*1536*4);
  float* igb  = (float*)alloc((size_t)NLAYER*1024*4);

  dim3 tb(32,8);
  pre_all<<<30376, tb, 0, stream>>>(qw,kw,vw,ow,iw,gw,f1w,f2w,outw,
                                    qb,kb,vb,ib,gb,
                                    qkvT,owT,igT,f1T,f2T,outT, qkvb,igb);
  embed_k<<<ROWS*DIM/4/256, 256, 0, stream>>>(x, tok_emb, pos_emb, h);

  constexpr size_t SM_MID3 = 3*(128+128)*32*2;  // 48 KiB
  constexpr size_t SM_ROW3 = 3*(64+128)*32*2;   // 36 KiB
  constexpr size_t SM_VOC  = 2*(128+128)*64*2;  // 64 KiB -> 2 blocks/CU

  for (int l=0;l<NLAYER;l++){
    ln_k<<<ROWS/4, 256, 0, stream>>>(h, n1w + l*DIM, n1b + l*DIM, hn);
    gemm_p<64,128,32,1,4,3,7,1><<<dim3(ROWS/64, 1536/128), 256, SM_ROW3, stream>>>(
        hn, qkvT + (size_t)l*1536*DIM, qkvb + l*1536, nullptr,
        nullptr, qkvB, vTb, ROWS, 1536, DIM);
    attn_k<<<dim3(SEQ/64, NH, BATCH), 256, 0, stream>>>(qkvB, vTb, qphase + l*NH, oB);
    gemm_p<64,128,32,1,4,3,4,1><<<dim3(ROWS/64, DIM/128), 256, SM_ROW3, stream>>>(
        oB, owT + (size_t)l*DIM*DIM, ob + l*DIM, sp_phase + l*DIM,
        h, nullptr, nullptr, ROWS, DIM, DIM);
    ln_k<<<ROWS/4, 256, 0, stream>>>(h, n2w + l*DIM, n2b + l*DIM, hn);
    gemm_p<128,128,32,2,2,3,3,1><<<dim3(ROWS/128, FFD/128), 256, SM_MID3, stream>>>(
        hn, f1T + (size_t)l*DIM*FFD, f1b + l*FFD, nullptr,
        nullptr, ffB, nullptr, ROWS, FFD, DIM);
    gemm_p<64,128,32,1,4,3,6,1><<<dim3(ROWS/64, DIM/128), 256, SM_ROW3, stream>>>(
        ffB, f2T + (size_t)l*DIM*FFD, f2b + l*DIM, nullptr,
        h, hB, nullptr, ROWS, DIM, FFD);
    gemm_p<128,128,32,2,2,3,5,1><<<dim3(ROWS/128, 1024/128), 256, SM_MID3, stream>>>(
        hB, igT + (size_t)l*1024*DIM, igb + l*1024, nullptr,
        h, nullptr, nullptr, ROWS, 1024, DIM);
  }
  ln_k<<<ROWS/4, 256, 0, stream>>>(h, nw, nb, hn);
  gemm_p<128,128,64,2,2,2,8,0><<<dim3(ROWS/128, VOCAB/128), 256, SM_VOC, stream>>>(
      hn, outT, outb, nullptr, out, nullptr, nullptr, ROWS, VOCAB, DIM);
}

// Round 14
// 1051.851 us; speedup vs baseline: 1.0098x; 1.0098x over previous
//
#include <hip/hip_runtime.h>
#include <math.h>

#define DIM 512
#define NH 8
#define HD 64
#define SEQ 2048
#define BATCH 2
#define NLAYER 4
#define FFD 2048
#define VOCAB 32000
#define ROWS (BATCH*SEQ)   // 4096
#define QKV_LD 1536

typedef unsigned short u16;
typedef __attribute__((ext_vector_type(8))) short bfrag;   // 8 x bf16 (4 VGPRs)
typedef __attribute__((ext_vector_type(4))) short sfrag4;  // 4 x bf16 (8B)
typedef __attribute__((ext_vector_type(4))) float facc;    // 4 x f32

__device__ __forceinline__ u16 f2bf(float f){
  unsigned u = __builtin_bit_cast(unsigned, f);
  u += 0x7fff + ((u>>16)&1);          // RNE
  return (u16)(u>>16);
}

typedef __attribute__((address_space(3))) unsigned int lds_u32;
typedef const __attribute__((address_space(1))) unsigned int glob_u32;
__device__ __forceinline__ void gload16(const void* g, void* l){
  __builtin_amdgcn_global_load_lds((glob_u32*)g, (lds_u32*)l, 16, 0, 0);
}

template<int N> __device__ __forceinline__ void wait_vmcnt(){
  if constexpr (N==0)       asm volatile("s_waitcnt vmcnt(0)" ::: "memory");
  else if constexpr (N==3)  asm volatile("s_waitcnt vmcnt(3)" ::: "memory");
  else if constexpr (N==4)  asm volatile("s_waitcnt vmcnt(4)" ::: "memory");
  else if constexpr (N==6)  asm volatile("s_waitcnt vmcnt(6)" ::: "memory");
  else if constexpr (N==8)  asm volatile("s_waitcnt vmcnt(8)" ::: "memory");
  else if constexpr (N==16) asm volatile("s_waitcnt vmcnt(16)" ::: "memory");
  else static_assert(N==0, "unsupported vmcnt");
}

// ============ unified preprocessing: 9 transposes + 2 bias concats ===========
__device__ __forceinline__ void do_transpose(
    const float* __restrict__ I, u16* __restrict__ O,
    int K, int N, int nx, int ky, int imode){
  __shared__ float t[32][33];
  const int n0 = nx*32, k0 = ky*32;
  #pragma unroll
  for (int i=0;i<4;i++){
    int k = k0 + threadIdx.y + 8*i;
    t[threadIdx.y+8*i][threadIdx.x] = I[(size_t)k*N + n0 + threadIdx.x];
  }
  __syncthreads();
  #pragma unroll
  for (int i=0;i<4;i++){
    int n = n0 + threadIdx.y + 8*i;
    int np = (imode==0) ? n : ((n>>4)*32 + (n&15) + (imode==2 ? 16 : 0));
    O[(size_t)np*K + k0 + threadIdx.x] = f2bf(t[threadIdx.x][threadIdx.y+8*i]);
  }
}

__global__ void pre_all(
    const float* qw, const float* kw, const float* vw, const float* ow,
    const float* iw, const float* gw, const float* f1w, const float* f2w,
    const float* outw,
    const float* qb, const float* kb, const float* vb,
    const float* ib, const float* gb,
    u16* qkvT, u16* owT, u16* igT, u16* f1T, u16* f2T, u16* outT,
    float* qkvb, float* igb){
  const int bid = blockIdx.x;
  if (bid < 6144){                                   // jobs 0-5: 512x512 per layer
    int job = bid >> 10, local = bid & 1023;
    int l = local >> 8, rr = local & 255;
    int nx = rr & 15, ky = rr >> 4;
    const float* src; u16* dst; int im = 0;
    switch(job){
      case 0: src=qw+(size_t)l*262144; dst=qkvT+(size_t)l*786432;        break;
      case 1: src=kw+(size_t)l*262144; dst=qkvT+(size_t)l*786432+262144; break;
      case 2: src=vw+(size_t)l*262144; dst=qkvT+(size_t)l*786432+524288; break;
      case 3: src=ow+(size_t)l*262144; dst=owT +(size_t)l*262144;        break;
      case 4: src=iw+(size_t)l*262144; dst=igT +(size_t)l*524288; im=1;  break;
      default:src=gw+(size_t)l*262144; dst=igT +(size_t)l*524288; im=2;  break;
    }
    do_transpose(src, dst, 512, 512, nx, ky, im);
  } else if (bid < 10240){                           // job 6: f1w 512x2048
    int local = bid - 6144;
    int l = local >> 10, rr = local & 1023;
    int nx = rr & 63, ky = rr >> 6;
    do_transpose(f1w+(size_t)l*1048576, f1T+(size_t)l*1048576, 512, 2048, nx, ky, 0);
  } else if (bid < 14336){                           // job 7: f2w 2048x512
    int local = bid - 10240;
    int l = local >> 10, rr = local & 1023;
    int nx = rr & 15, ky = rr >> 4;
    do_transpose(f2w+(size_t)l*1048576, f2T+(size_t)l*1048576, 2048, 512, nx, ky, 0);
  } else if (bid < 30336){                           // job 8: outw 512x32000
    int local = bid - 14336;
    int nx = local % 1000, ky = local / 1000;
    do_transpose(outw, outT, 512, 32000, nx, ky, 0);
  } else if (bid < 30360){                           // concat3: qkv bias
    int tid = threadIdx.y*32 + threadIdx.x;
    int idx = (bid-30336)*256 + tid;                 // < 6144
    int l = idx/1536, r2 = idx%1536;
    qkvb[idx] = (r2<512) ? qb[l*512+r2] : (r2<1024 ? kb[l*512+r2-512] : vb[l*512+r2-1024]);
  } else {                                           // concat2i: interleaved i/g bias
    int tid = threadIdx.y*32 + threadIdx.x;
    int idx = (bid-30360)*256 + tid;                 // < 4096
    int l = idx>>10, cp = idx&1023;
    int bb = cp>>4, c = (bb>>1)*16 + (cp&15);
    igb[idx] = (bb&1) ? gb[l*512+c] : ib[l*512+c];
  }
}

// ---------------- embedding ---------------------------------------------------
__global__ void embed_k(const int* __restrict__ x, const float* __restrict__ tok,
                        const float* __restrict__ pos, float* __restrict__ h){
  int idx = blockIdx.x*256 + threadIdx.x;     // over ROWS*DIM/4
  int row = idx >> 7;
  int d4  = idx & 127;
  int s   = row & (SEQ-1);
  int tkn = x[row];
  float4 tv = *(const float4*)(tok + (size_t)tkn*DIM + d4*4);
  float4 pv = *(const float4*)(pos + (size_t)s*DIM + d4*4);
  float4 r; r.x=tv.x+pv.x; r.y=tv.y+pv.y; r.z=tv.z+pv.z; r.w=tv.w+pv.w;
  *(float4*)(h + (size_t)row*DIM + d4*4) = r;
}

// ---------------- layernorm: f32 in -> bf16 out ------------------------------
__global__ __launch_bounds__(256) void ln_k(const float* __restrict__ h,
    const float* __restrict__ w, const float* __restrict__ bsc,
    u16* __restrict__ out){
  const int wid = threadIdx.x>>6, lane = threadIdx.x&63;
  const int row = blockIdx.x*4 + wid;
  const float* r = h + (size_t)row*DIM + lane*8;
  float4 v0 = *(const float4*)r;
  float4 v1 = *(const float4*)(r+4);
  float s  = v0.x+v0.y+v0.z+v0.w + v1.x+v1.y+v1.z+v1.w;
  float ss = v0.x*v0.x+v0.y*v0.y+v0.z*v0.z+v0.w*v0.w
           + v1.x*v1.x+v1.y*v1.y+v1.z*v1.z+v1.w*v1.w;
  #pragma unroll
  for (int m=1;m<64;m<<=1){ s += __shfl_xor(s,m); ss += __shfl_xor(ss,m); }
  const float mean = s*(1.f/DIM);
  const float var  = ss*(1.f/DIM) - mean*mean;
  const float rsd  = rsqrtf(var + 1e-5f);
  float4 w0 = *(const float4*)(w + lane*8);
  float4 w1 = *(const float4*)(w + lane*8 + 4);
  float4 b0 = *(const float4*)(bsc + lane*8);
  float4 b1 = *(const float4*)(bsc + lane*8 + 4);
  bfrag pk;
  pk[0]=(short)f2bf((v0.x-mean)*rsd*w0.x+b0.x);
  pk[1]=(short)f2bf((v0.y-mean)*rsd*w0.y+b0.y);
  pk[2]=(short)f2bf((v0.z-mean)*rsd*w0.z+b0.z);
  pk[3]=(short)f2bf((v0.w-mean)*rsd*w0.w+b0.w);
  pk[4]=(short)f2bf((v1.x-mean)*rsd*w1.x+b1.x);
  pk[5]=(short)f2bf((v1.y-mean)*rsd*w1.y+b1.y);
  pk[6]=(short)f2bf((v1.z-mean)*rsd*w1.z+b1.z);
  pk[7]=(short)f2bf((v1.w-mean)*rsd*w1.w+b1.w);
  *(bfrag*)&out[(size_t)row*DIM + lane*8] = pk;
}

// ---------------- pipelined GEMM: C[M,N] = A[M,K](bf16) * BT[N,K]^T + bias ---
// MODE 0: Cf = v                        3: Cb = bf16(gelu(v))
// MODE 4: t=Cf+v; t*=cos(aux[col]*t); Cf=t        (residual+superpos)
// MODE 5: interleaved i/g gate: Cf = i*sig(g) + Cf*(1-sig(g))
// MODE 6: t=Cf+v; Cf=t; Cb=bf16(t)                (residual + tobf)
// MODE 7: cols<1024 -> Cb (qkv); cols>=1024 -> vt transposed (V^T)
// MODE 8: Cf = v via nontemporal store (streaming logits)
template<int BM,int BN,int BK,int WRN,int WCN,int DEPTH,int MODE,int SWZ>
__global__ __launch_bounds__(WRN*WCN*64, 2) void gemm_p(
    const u16* __restrict__ A, const u16* __restrict__ BT,
    const float* __restrict__ bias, const float* __restrict__ aux,
    float* __restrict__ Cf, u16* __restrict__ Cb, u16* __restrict__ vt,
    int M, int N, int K){
  constexpr int NTH = WRN*WCN*64;
  constexpr int FI  = BM/(16*WRN);
  constexpr int FJ  = BN/(16*WCN);
  constexpr int CPR = BK/8;
  constexpr int LA  = BM*CPR/NTH;
  constexpr int LB  = BN*CPR/NTH;
  constexpr int LPT = LA+LB;
  constexpr int NKK = BK/32;
  extern __shared__ __align__(16) u16 smem[];
  u16* lds_a = smem;                     // [DEPTH][BM*BK]
  u16* lds_b = smem + DEPTH*BM*BK;       // [DEPTH][BN*BK]

  const int tid = threadIdx.x;
  const int wid = tid>>6, lane = tid&63;
  const int wr = wid / WCN, wc = wid % WCN;
  const int lr = lane&15, lg = lane>>4;
  int tm, tn;
  if constexpr (SWZ){
    const unsigned nwg = gridDim.x*gridDim.y;
    const unsigned lin = blockIdx.y*gridDim.x + blockIdx.x;
    const unsigned q = nwg >> 3;
    const unsigned sw = (lin & 7)*q + (lin >> 3);
    tm = sw % gridDim.x; tn = sw / gridDim.x;
  } else {
    tm = blockIdx.x; tn = blockIdx.y;
  }

  auto swzf = [](int row)->int{ return (BK==64) ? (row&7) : ((row>>1)&3); };

  auto stage = [&](int t, int buf){
    const int k0 = t*BK;
    #pragma unroll
    for (int i=0;i<LA;i++){
      int u = i*NTH + tid;
      int row = u/CPR, c = (u%CPR) ^ swzf(row);
      gload16(&A[(size_t)(tm*BM+row)*K + k0 + c*8], &lds_a[buf*BM*BK + u*8]);
    }
    #pragma unroll
    for (int i=0;i<LB;i++){
      int u = i*NTH + tid;
      int row = u/CPR, c = (u%CPR) ^ swzf(row);
      gload16(&BT[(size_t)(tn*BN+row)*K + k0 + c*8], &lds_b[buf*BN*BK + u*8]);
    }
  };

  facc acc[FI][FJ] = {};
  const int NT = K/BK;
  stage(0,0);
  if (NT>1) stage(1,1);
  if constexpr (DEPTH==3) { if (NT>2) stage(2,2); }
  for (int t=0;t<NT;t++){
    const int buf = t % DEPTH;
    const u16* la = &lds_a[buf*BM*BK];
    const u16* lb = &lds_b[buf*BN*BK];
    const int rem = NT-1-t;
    if constexpr (DEPTH==3){
      if (rem >= 2) wait_vmcnt<2*LPT>();
      else if (rem == 1) wait_vmcnt<LPT>();
      else wait_vmcnt<0>();
    } else {
      if (rem >= 1) wait_vmcnt<LPT>(); else wait_vmcnt<0>();
    }
    __builtin_amdgcn_s_barrier();
    __builtin_amdgcn_sched_barrier(0);
    bfrag af[FI], bf[FJ];
    #pragma unroll
    for (int i=0;i<FI;i++){
      int row = wr*(FI*16) + i*16 + lr;
      af[i] = *(const bfrag*)&la[row*BK + ((lg ^ swzf(row))*8)];
    }
    #pragma unroll
    for (int j=0;j<FJ;j++){
      int row = wc*(FJ*16) + j*16 + lr;
      bf[j] = *(const bfrag*)&lb[row*BK + ((lg ^ swzf(row))*8)];
    }
    if constexpr (NKK==1){
      asm volatile("s_waitcnt lgkmcnt(0)" ::: "memory");
      __builtin_amdgcn_sched_barrier(0);
      __builtin_amdgcn_s_barrier();
      __builtin_amdgcn_sched_barrier(0);
      if (t+DEPTH<NT) stage(t+DEPTH, buf);
      __builtin_amdgcn_s_setprio(1);
      #pragma unroll
      for (int i=0;i<FI;i++)
        #pragma unroll
        for (int j=0;j<FJ;j++)
          acc[i][j] = __builtin_amdgcn_mfma_f32_16x16x32_bf16(af[i], bf[j], acc[i][j],0,0,0);
      __builtin_amdgcn_s_setprio(0);
    } else {
      __builtin_amdgcn_s_setprio(1);
      #pragma unroll
      for (int i=0;i<FI;i++)
        #pragma unroll
        for (int j=0;j<FJ;j++)
          acc[i][j] = __builtin_amdgcn_mfma_f32_16x16x32_bf16(af[i], bf[j], acc[i][j],0,0,0);
      __builtin_amdgcn_s_setprio(0);
      bfrag af1[FI], bf1[FJ];
      #pragma unroll
      for (int i=0;i<FI;i++){
        int row = wr*(FI*16) + i*16 + lr;
        af1[i] = *(const bfrag*)&la[row*BK + (((4+lg) ^ swzf(row))*8)];
      }
      #pragma unroll
      for (int j=0;j<FJ;j++){
        int row = wc*(FJ*16) + j*16 + lr;
        bf1[j] = *(const bfrag*)&lb[row*BK + (((4+lg) ^ swzf(row))*8)];
      }
      asm volatile("s_waitcnt lgkmcnt(0)" ::: "memory");
      __builtin_amdgcn_sched_barrier(0);
      __builtin_amdgcn_s_barrier();
      __builtin_amdgcn_sched_barrier(0);
      if (t+DEPTH<NT) stage(t+DEPTH, buf);
      __builtin_amdgcn_s_setprio(1);
      #pragma unroll
      for (int i=0;i<FI;i++)
        #pragma unroll
        for (int j=0;j<FJ;j++)
          acc[i][j] = __builtin_amdgcn_mfma_f32_16x16x32_bf16(af1[i], bf1[j], acc[i][j],0,0,0);
      __builtin_amdgcn_s_setprio(0);
    }
  }

  if constexpr (MODE==5){
    #pragma unroll
    for (int i=0;i<FI;i++){
      #pragma unroll
      for (int j=0;j<FJ;j+=2){
        const int colp = tn*BN + wc*(FJ*16) + j*16;  // even 16-block (i-half)
        const int c = (colp>>5)*16 + lr;             // true output col
        const float bi = bias[colp + lr];
        const float bg = bias[colp + 16 + lr];
        #pragma unroll
        for (int r=0;r<4;r++){
          const int row = tm*BM + wr*(FI*16) + i*16 + lg*4 + r;
          float vi = acc[i][j][r]   + bi;
          float vg = acc[i][j+1][r] + bg;
          float g  = 1.f/(1.f+__expf(-vg));
          const size_t o = (size_t)row*DIM + c;
          float hv = Cf[o];
          Cf[o] = vi*g + hv*(1.f-g);
        }
      }
    }
  } else if constexpr (MODE==7){
    #pragma unroll
    for (int i=0;i<FI;i++){
      #pragma unroll
      for (int j=0;j<FJ;j++){
        const int colblk = tn*BN + wc*(FJ*16) + j*16;
        const float bv = bias[colblk + lr];
        if (colblk < 1024){
          #pragma unroll
          for (int r=0;r<4;r++){
            const int row = tm*BM + wr*(FI*16) + i*16 + lg*4 + r;
            Cb[(size_t)row*N + colblk + lr] = f2bf(acc[i][j][r] + bv);
          }
        } else {
          const int c = colblk + lr - 1024;
          const int hh = c>>6, d = c&63;
          const int row0 = tm*BM + wr*(FI*16) + i*16 + lg*4;
          const int b = row0>>11, s0 = row0&2047;
          sfrag4 pk;
          #pragma unroll
          for (int r=0;r<4;r++) pk[r] = (short)f2bf(acc[i][j][r] + bv);
          *(sfrag4*)&vt[((size_t)((b*NH+hh)*HD + d))*SEQ + s0] = pk;
        }
      }
    }
  } else {
    #pragma unroll
    for (int i=0;i<FI;i++){
      #pragma unroll
      for (int j=0;j<FJ;j++){
        const int col = tn*BN + wc*(FJ*16) + j*16 + lr;
        const float bv = bias ? bias[col] : 0.f;
        #pragma unroll
        for (int r=0;r<4;r++){
          const int row = tm*BM + wr*(FI*16) + i*16 + lg*4 + r;
          float v = acc[i][j][r] + bv;
          const size_t o = (size_t)row*N + col;
          if      (MODE==0) Cf[o] = v;
          else if (MODE==8) __builtin_nontemporal_store(v, &Cf[o]);
          else if (MODE==3){ float g = 0.5f*v*(1.f+erff(v*0.70710678118f)); Cb[o] = f2bf(g); }
          else if (MODE==4){ float t = Cf[o] + v; t = t*__cosf(aux[col]*t); Cf[o] = t; }
          else if (MODE==6){ float t = Cf[o] + v; Cf[o] = t; Cb[o] = f2bf(t); }
        }
      }
    }
  }
}

// ---------------- fused causal attention (v1 structure, fixed-shift softmax) --
__global__ __launch_bounds__(256) void attn_k(
    const u16* __restrict__ QKV, const u16* __restrict__ VT,
    const float* __restrict__ qphase, u16* __restrict__ O){
  __shared__ __align__(16) u16 lds_p[4][16*32];
  const int qblk = blockIdx.x, hh = blockIdx.y, b = blockIdx.z;
  const int tid = threadIdx.x;
  const int wid = tid>>6, lane = tid&63;
  const int lr = lane&15, lg = lane>>4;
  const int qbase = qblk*64 + wid*16;
  const float ph = qphase[hh];
  const float scale = 0.125f;               // 1/sqrt(64)
  u16* pbuf = lds_p[wid];

  bfrag aq[2];
  #pragma unroll
  for (int st=0; st<2; st++)
    aq[st] = *(const bfrag*)&QKV[(size_t)(b*SEQ + qbase + lr)*QKV_LD + hh*HD + st*32 + lg*8];

  facc oacc[4];
  #pragma unroll
  for (int n=0;n<4;n++) oacc[n] = (facc){0.f,0.f,0.f,0.f};
  float lrow[4] = {0.f,0.f,0.f,0.f};

  const int nkv = (qbase + 15)/32 + 1;
  for (int kt=0; kt<nkv; kt++){
    const int kv0 = kt*32;
    facc sc[2];
    #pragma unroll
    for (int j=0;j<2;j++){
      bfrag bk0 = *(const bfrag*)&QKV[(size_t)(b*SEQ + kv0 + j*16 + lr)*QKV_LD + 512 + hh*HD + lg*8];
      bfrag bk1 = *(const bfrag*)&QKV[(size_t)(b*SEQ + kv0 + j*16 + lr)*QKV_LD + 512 + hh*HD + 32 + lg*8];
      facc z = (facc){0.f,0.f,0.f,0.f};
      z     = __builtin_amdgcn_mfma_f32_16x16x32_bf16(aq[0], bk0, z, 0,0,0);
      sc[j] = __builtin_amdgcn_mfma_f32_16x16x32_bf16(aq[1], bk1, z, 0,0,0);
    }
    bfrag vbf[4];
    #pragma unroll
    for (int n=0;n<4;n++)
      vbf[n] = *(const bfrag*)&VT[((size_t)((b*NH + hh)*HD + n*16 + lr))*SEQ + kv0 + lg*8];

    float pv[2][4];
    #pragma unroll
    for (int j=0;j<2;j++)
      #pragma unroll
      for (int r=0;r<4;r++){
        int srow = qbase + lg*4 + r;
        int scol = kv0 + j*16 + lr;
        float xv = sc[j][r]*scale;
        xv = xv*(1.f + 0.1f*__cosf(ph*xv));
        if (scol > srow) xv = -1e30f;
        pv[j][r] = __expf(xv);
      }
    #pragma unroll
    for (int r=0;r<4;r++){
      float rs = pv[0][r] + pv[1][r];
      rs += __shfl_xor(rs,1);
      rs += __shfl_xor(rs,2);
      rs += __shfl_xor(rs,4);
      rs += __shfl_xor(rs,8);
      lrow[r] += rs;
    }
    #pragma unroll
    for (int j=0;j<2;j++)
      #pragma unroll
      for (int r=0;r<4;r++)
        pbuf[(lg*4+r)*32 + j*16 + lr] = f2bf(pv[j][r]);
    bfrag pa = *(const bfrag*)&pbuf[lr*32 + lg*8];
    #pragma unroll
    for (int n=0;n<4;n++)
      oacc[n] = __builtin_amdgcn_mfma_f32_16x16x32_bf16(pa, vbf[n], oacc[n], 0,0,0);
  }
  float rcp[4];
  #pragma unroll
  for (int r=0;r<4;r++) rcp[r] = 1.f/lrow[r];
  #pragma unroll
  for (int n=0;n<4;n++)
    #pragma unroll
    for (int r=0;r<4;r++){
      float val = oacc[n][r] * rcp[r];
      O[(size_t)(b*SEQ + qbase + lg*4 + r)*DIM + hh*HD + n*16 + lr] = f2bf(val);
    }
}

// ---------------- host -------------------------------------------------------
extern "C" void kernel_launch(void* const* d_in, const int* in_sizes, int n_in,
                              void* d_out, int out_size, void* d_ws, size_t ws_size,
                              hipStream_t stream){
  const int*   x        = (const int*)d_in[0];
  const float* tok_emb  = (const float*)d_in[1];
  const float* pos_emb  = (const float*)d_in[2];
  const float* qw = (const float*)d_in[3];  const float* qb = (const float*)d_in[4];
  const float* kw = (const float*)d_in[5];  const float* kb = (const float*)d_in[6];
  const float* vw = (const float*)d_in[7];  const float* vb = (const float*)d_in[8];
  const float* ow = (const float*)d_in[9];  const float* ob = (const float*)d_in[10];
  const float* qphase   = (const float*)d_in[11];
  const float* sp_phase = (const float*)d_in[12];
  const float* n1w = (const float*)d_in[13]; const float* n1b = (const float*)d_in[14];
  const float* n2w = (const float*)d_in[15]; const float* n2b = (const float*)d_in[16];
  const float* f1w = (const float*)d_in[17]; const float* f1b = (const float*)d_in[18];
  const float* f2w = (const float*)d_in[19]; const float* f2b = (const float*)d_in[20];
  const float* iw  = (const float*)d_in[21]; const float* ib  = (const float*)d_in[22];
  const float* gw  = (const float*)d_in[23]; const float* gb  = (const float*)d_in[24];
  const float* nw  = (const float*)d_in[25]; const float* nb  = (const float*)d_in[26];
  const float* outw= (const float*)d_in[27]; const float* outb= (const float*)d_in[28];
  float* out = (float*)d_out;

  char* base = (char*)d_ws;
  size_t off = 0;
  auto alloc = [&](size_t bytes)->void*{
    void* p = base + off; off += bytes; off = (off + 255) & ~(size_t)255; return p;
  };
  float* h    = (float*)alloc((size_t)ROWS*DIM*4);
  u16* hn     = (u16*)alloc((size_t)ROWS*DIM*2);
  u16* qkvB   = (u16*)alloc((size_t)ROWS*QKV_LD*2);
  u16* vTb    = (u16*)alloc((size_t)ROWS*DIM*2);
  u16* oB     = (u16*)alloc((size_t)ROWS*DIM*2);
  u16* hB     = (u16*)alloc((size_t)ROWS*DIM*2);
  u16* ffB    = (u16*)alloc((size_t)ROWS*FFD*2);
  u16* qkvT = (u16*)alloc((size_t)NLAYER*1536*DIM*2);
  u16* owT  = (u16*)alloc((size_t)NLAYER*DIM*DIM*2);
  u16* igT  = (u16*)alloc((size_t)NLAYER*1024*DIM*2);
  u16* f1T  = (u16*)alloc((size_t)NLAYER*DIM*FFD*2);
  u16* f2T  = (u16*)alloc((size_t)NLAYER*DIM*FFD*2);
  u16* outT = (u16*)alloc((size_t)VOCAB*DIM*2);
  float* qkvb = (float*)alloc((size_t)NLAYER*1536*4);
  float* igb  = (float*)alloc((size_t)NLAYER*1024*4);

  dim3 tb(32,8);
  pre_all<<<30376, tb, 0, stream>>>(qw,kw,vw,ow,iw,gw,f1w,f2w,outw,
                                    qb,kb,vb,ib,gb,
                                    qkvT,owT,igT,f1T,f2T,outT, qkvb,igb);
  embed_k<<<ROWS*DIM/4/256, 256, 0, stream>>>(x, tok_emb, pos_emb, h);

  constexpr size_t SM_MID3 = 3*(128+128)*32*2;  // 48 KiB
  constexpr size_t SM_ROW3 = 3*(64+128)*32*2;   // 36 KiB
  constexpr size_t SM_VOC3 = 3*(128+128)*32*2;  // 48 KiB

  for (int l=0;l<NLAYER;l++){
    ln_k<<<ROWS/4, 256, 0, stream>>>(h, n1w + l*DIM, n1b + l*DIM, hn);
    gemm_p<128,128,32,2,2,3,7,1><<<dim3(ROWS/128, 1536/128), 256, SM_MID3, stream>>>(
        hn, qkvT + (size_t)l*1536*DIM, qkvb + l*1536, nullptr,
        nullptr, qkvB, vTb, ROWS, 1536, DIM);
    attn_k<<<dim3(SEQ/64, NH, BATCH), 256, 0, stream>>>(qkvB, vTb, qphase + l*NH, oB);
    gemm_p<64,128,32,1,4,3,4,1><<<dim3(ROWS/64, DIM/128), 256, SM_ROW3, stream>>>(
        oB, owT + (size_t)l*DIM*DIM, ob + l*DIM, sp_phase + l*DIM,
        h, nullptr, nullptr, ROWS, DIM, DIM);
    ln_k<<<ROWS/4, 256, 0, stream>>>(h, n2w + l*DIM, n2b + l*DIM, hn);
    gemm_p<128,128,32,2,2,3,3,1><<<dim3(ROWS/128, FFD/128), 256, SM_MID3, stream>>>(
        hn, f1T + (size_t)l*DIM*FFD, f1b + l*FFD, nullptr,
        nullptr, ffB, nullptr, ROWS, FFD, DIM);
    gemm_p<64,128,32,1,4,3,6,1><<<dim3(ROWS/64, DIM/128), 256, SM_ROW3, stream>>>(
        ffB, f2T + (size_t)l*DIM*FFD, f2b + l*DIM, nullptr,
        h, hB, nullptr, ROWS, DIM, FFD);
    gemm_p<64,128,32,1,4,3,5,1><<<dim3(ROWS/64, 1024/128), 256, SM_ROW3, stream>>>(
        hB, igT + (size_t)l*1024*DIM, igb + l*1024, nullptr,
        h, nullptr, nullptr, ROWS, 1024, DIM);
  }
  ln_k<<<ROWS/4, 256, 0, stream>>>(h, nw, nb, hn);
  gemm_p<128,128,32,2,2,3,8,0><<<dim3(ROWS/128, VOCAB/128), 256, SM_VOC3, stream>>>(
      hn, outT, outb, nullptr, out, nullptr, nullptr, ROWS, VOCAB, DIM);
}